// Round 1
// baseline (1210.743 us; speedup 1.0000x reference)
//
#include <hip/hip_runtime.h>

typedef unsigned int uint32;
typedef unsigned short ushort16;

typedef __attribute__((ext_vector_type(8))) short bf16x8;
typedef __attribute__((ext_vector_type(4))) float f32x4;

#define NNODES 32768
#define DFEAT 384
#define KPAD1 320

__device__ __forceinline__ float bf2f(ushort16 u) {
  union { uint32 i; float f; } x; x.i = ((uint32)u) << 16; return x.f;
}
__device__ __forceinline__ ushort16 f2bf(float f) {
  union { float f; uint32 i; } x; x.f = f;
  uint32 r = (x.i + 0x7fffu + ((x.i >> 16) & 1u)) >> 16;
  return (ushort16)r;
}

// ---------------- x_nodes f32 [32768,300] -> bf16 [32768,320] (zero-padded) --
__global__ void convert_x_kernel(const float* __restrict__ X, ushort16* __restrict__ A0) {
  const int total = NNODES * KPAD1;
  for (int idx = blockIdx.x * blockDim.x + threadIdx.x; idx < total;
       idx += gridDim.x * blockDim.x) {
    int row = idx / KPAD1, col = idx - row * KPAD1;
    float v = (col < 300) ? X[(size_t)row * 300 + col] : 0.f;
    A0[idx] = f2bf(v);
  }
}

// ---------------- H_sent = mean_s 0.5*(last+first)  [64,768] ----------------
__global__ void sent_mean_kernel(const float* __restrict__ last,
                                 const float* __restrict__ first,
                                 float* __restrict__ H) {
  int b = blockIdx.x, sc = blockIdx.y, e = threadIdx.x;  // block 768
  int s0 = sc * 32;
  const float* pl = last + ((size_t)b * 512 + s0) * 768 + e;
  const float* pf = first + ((size_t)b * 512 + s0) * 768 + e;
  float s = 0.f;
  for (int i = 0; i < 32; ++i) s += pl[i * 768] + pf[i * 768];
  atomicAdd(&H[b * 768 + e], s * (0.5f / 512.f));
}

// ---------------- degree / CSR build ----------------------------------------
__global__ void deg_count_kernel(const int* __restrict__ dst, int* __restrict__ cnt, int E) {
  int e = blockIdx.x * blockDim.x + threadIdx.x;
  if (e < E) atomicAdd(&cnt[dst[e]], 1);
}
__global__ void disq_kernel(const int* __restrict__ cnt, float* __restrict__ disq) {
  int n = blockIdx.x * blockDim.x + threadIdx.x;
  if (n < NNODES) disq[n] = rsqrtf((float)cnt[n] + 1.0f);  // +1 self loop
}
// single-block exclusive scan of 32768 counts -> row_start, cursor; row_start[N]=E
__global__ void scan_kernel(const int* __restrict__ cnt, int* __restrict__ row_start,
                            int* __restrict__ cursor) {
  __shared__ int buf[1024];
  int t = threadIdx.x;
  int base = t * 32;
  int s = 0;
  for (int i = 0; i < 32; ++i) s += cnt[base + i];
  buf[t] = s; __syncthreads();
  int x = s;
  for (int off = 1; off < 1024; off <<= 1) {
    int v = (t >= off) ? buf[t - off] : 0;
    __syncthreads();
    x += v; buf[t] = x;
    __syncthreads();
  }
  int run = x - s;  // exclusive prefix
  for (int i = 0; i < 32; ++i) {
    row_start[base + i] = run; cursor[base + i] = run;
    run += cnt[base + i];
  }
  if (t == 1023) row_start[NNODES] = run;
}
__global__ void scatter_kernel(const int* __restrict__ src, const int* __restrict__ dst,
                               int* __restrict__ cursor, int* __restrict__ csr, int E) {
  int e = blockIdx.x * blockDim.x + threadIdx.x;
  if (e < E) {
    int d = dst[e];
    int pos = atomicAdd(&cursor[d], 1);
    csr[pos] = src[e];
  }
}

// ---------------- weight transform: BT[n][k] = a[k]*W[k][n] (bf16), ---------
// ----------------                  bias_out[n] = bias[n] + sum_k sh[k]*W[k][n]
__global__ void xform_w_kernel(const float* __restrict__ W, const float* __restrict__ bias,
                               const float* __restrict__ a, const float* __restrict__ sh,
                               ushort16* __restrict__ BT, float* __restrict__ bias_out,
                               int K, int Kpad, int Nw) {
  __shared__ float red[128];
  int n = blockIdx.x, t = threadIdx.x;
  float part = 0.f;
  for (int k = t; k < Kpad; k += 128) {
    ushort16 o = 0; float contrib = 0.f;
    if (k < K) {
      float w = W[(size_t)k * Nw + n];
      float ak = a ? a[k] : 1.f;
      float shk = sh ? sh[k] : 0.f;
      o = f2bf(ak * w);
      contrib = shk * w;
    }
    BT[(size_t)n * Kpad + k] = o;
    part += contrib;
  }
  red[t] = part; __syncthreads();
  for (int off = 64; off > 0; off >>= 1) {
    if (t < off) red[t] += red[t + off];
    __syncthreads();
  }
  if (t == 0) bias_out[n] = (bias ? bias[n] : 0.f) + red[0];
}

// ---------------- per-column stats of bf16 activation [32768,384] -----------
__global__ void stats_kernel(const ushort16* __restrict__ X, float* __restrict__ stat,
                             int rows_per_block) {
  int c = threadIdx.x;  // 384
  int r0 = blockIdx.x * rows_per_block;
  float s = 0.f, q = 0.f;
  for (int r = 0; r < rows_per_block; ++r) {
    float v = bf2f(X[(size_t)(r0 + r) * DFEAT + c]);
    s += v; q += v * v;
  }
  atomicAdd(&stat[c], s);
  atomicAdd(&stat[DFEAT + c], q);
}
__global__ void make_affine_kernel(const float* __restrict__ stat, const float* __restrict__ g,
                                   const float* __restrict__ b, float* __restrict__ a,
                                   float* __restrict__ sh, float invN) {
  int c = threadIdx.x;  // 384
  float mean = stat[c] * invN;
  float var = stat[DFEAT + c] * invN - mean * mean;
  float ac = g[c] * rsqrtf(var + 1e-5f);
  a[c] = ac; sh[c] = b[c] - ac * mean;
}

// ---------------- MFMA bf16 GEMM: C[M,384] = A[M,K] @ BT[384,K]^T + bias ----
#define BM 128
#define BN 128
#define BKT 32
#define LDT 40  // BKT + 8 pad (shorts); row pitch 80 B (16B-aligned, conflict-light)

template <bool RELU>
__global__ __launch_bounds__(256) void gemm_bf16(
    const ushort16* __restrict__ A, int lda, const ushort16* __restrict__ BT, int ldb,
    const float* __restrict__ bias, ushort16* __restrict__ C, int Ntot, int K) {
  __shared__ __attribute__((aligned(16))) ushort16 As[BM * LDT];
  __shared__ __attribute__((aligned(16))) ushort16 Bs[BN * LDT];
  int bm0 = blockIdx.x * BM, bn0 = blockIdx.y * BN;
  int tid = threadIdx.x;
  int lane = tid & 63, wave = tid >> 6;
  int wm = (wave & 1) * 64, wn = (wave >> 1) * 64;
  int l15 = lane & 15, quad = lane >> 4;

  f32x4 acc[4][4];
  for (int i = 0; i < 4; ++i)
    for (int j = 0; j < 4; ++j) acc[i][j] = (f32x4)0.f;

  for (int kk = 0; kk < K; kk += BKT) {
    __syncthreads();
    // stage 128x32 A-tile and 128x32 BT-tile; 512 16B-chunks each, 2/thread
    for (int i = 0; i < 2; ++i) {
      int chunk = tid + i * 256;
      int row = chunk >> 2, cc = chunk & 3;
      uint4 va = *(const uint4*)(A + (size_t)(bm0 + row) * lda + kk + cc * 8);
      *(uint4*)(&As[row * LDT + cc * 8]) = va;
      uint4 vb = *(const uint4*)(BT + (size_t)(bn0 + row) * ldb + kk + cc * 8);
      *(uint4*)(&Bs[row * LDT + cc * 8]) = vb;
    }
    __syncthreads();
    bf16x8 af[4], bfr[4];
    for (int mi = 0; mi < 4; ++mi)
      af[mi] = *(const bf16x8*)(&As[(wm + mi * 16 + l15) * LDT + quad * 8]);
    for (int ni = 0; ni < 4; ++ni)
      bfr[ni] = *(const bf16x8*)(&Bs[(wn + ni * 16 + l15) * LDT + quad * 8]);
    for (int mi = 0; mi < 4; ++mi)
      for (int ni = 0; ni < 4; ++ni)
        acc[mi][ni] = __builtin_amdgcn_mfma_f32_16x16x32_bf16(af[mi], bfr[ni], acc[mi][ni], 0, 0, 0);
  }
  // epilogue: C/D layout col=lane&15, row=quad*4+reg (m89/m91-verified)
  for (int ni = 0; ni < 4; ++ni) {
    int col = bn0 + wn + ni * 16 + l15;
    float bv = bias[col];
    for (int mi = 0; mi < 4; ++mi) {
      for (int r = 0; r < 4; ++r) {
        int row = bm0 + wm + mi * 16 + quad * 4 + r;
        float v = acc[mi][ni][r] + bv;
        if (RELU) v = fmaxf(v, 0.f);
        C[(size_t)row * Ntot + col] = f2bf(v);
      }
    }
  }
}

// ---------------- GCN aggregation: RC = relu(Â·XW + b_conv), bf16 ----------
__global__ void aggregate_kernel(const uint32* __restrict__ XW2,  // [N][192] bf16-pairs
                                 const int* __restrict__ csr, const int* __restrict__ row_start,
                                 const float* __restrict__ disq, const float* __restrict__ bconv,
                                 uint32* __restrict__ RC2) {
  int n = blockIdx.x, c = threadIdx.x;  // 192 threads, 2 cols each
  float din = disq[n];
  uint32 sv = XW2[(size_t)n * 192 + c];
  float a0 = din * din * bf2f((ushort16)(sv & 0xffff));
  float a1 = din * din * bf2f((ushort16)(sv >> 16));
  int beg = row_start[n], end = row_start[n + 1];
  int sN = (beg < end) ? csr[beg] : 0;
  for (int i = beg; i < end; ++i) {
    int s = sN;
    if (i + 1 < end) sN = csr[i + 1];
    float w = din * disq[s];
    uint32 v = XW2[(size_t)s * 192 + c];
    a0 += w * bf2f((ushort16)(v & 0xffff));
    a1 += w * bf2f((ushort16)(v >> 16));
  }
  a0 = fmaxf(a0 + bconv[2 * c], 0.f);
  a1 = fmaxf(a1 + bconv[2 * c + 1], 0.f);
  RC2[(size_t)n * 192 + c] = (uint32)f2bf(a0) | ((uint32)f2bf(a1) << 16);
}

// ---------------- gather 2 masked nodes/sample + BN6 -> flat [64,768] f32 ---
__global__ void gather_kernel(const int* __restrict__ mask, const ushort16* __restrict__ R5,
                              const float* __restrict__ a, const float* __restrict__ sh,
                              float* __restrict__ flat) {
  __shared__ int smin, smax;
  int b = blockIdx.x, t = threadIdx.x;  // 384
  if (t == 0) { smin = 1 << 30; smax = -1; }
  __syncthreads();
  for (int p = t; p < 512; p += 384)
    if (mask[b * 512 + p]) { atomicMin(&smin, p); atomicMax(&smax, p); }
  __syncthreads();
  int sel[2] = {smin, smax};  // exactly 2 ones -> top_k tie order = ascending idx
  for (int j = 0; j < 2; ++j) {
    float v = bf2f(R5[(size_t)(b * 512 + sel[j]) * DFEAT + t]);
    flat[(size_t)b * 768 + j * DFEAT + t] = a[t] * v + sh[t];
  }
}

// ---------------- small tail: cat GEMM (f32) + batch BN + output ------------
__global__ void cat_gemm_kernel(const float* __restrict__ flat, const float* __restrict__ Wc,
                                const float* __restrict__ bc, float* __restrict__ out) {
  __shared__ float arow[768];
  int b = blockIdx.x, t = threadIdx.x;  // 256
  for (int k = t; k < 768; k += 256) arow[k] = flat[b * 768 + k];
  __syncthreads();
  for (int j = t; j < 768; j += 256) {
    float acc = bc[j];
    for (int k = 0; k < 768; ++k) acc += arow[k] * Wc[(size_t)k * 768 + j];
    out[b * 768 + j] = fmaxf(acc, 0.f);
  }
}
__global__ void stats64_kernel(const float* __restrict__ catrelu, const float* __restrict__ Hs,
                               const float* __restrict__ g, const float* __restrict__ bb,
                               float* __restrict__ aff) {
  int c = threadIdx.x;  // 768
  float s1 = 0, q1 = 0, s2 = 0, q2 = 0;
  for (int b = 0; b < 64; ++b) {
    float v = catrelu[b * 768 + c]; s1 += v; q1 += v * v;
    float h = Hs[b * 768 + c]; s2 += h; q2 += h * h;
  }
  const float inv = 1.0f / 64.0f;
  float m1 = s1 * inv, var1 = q1 * inv - m1 * m1;
  float a1 = g[c] * rsqrtf(var1 + 1e-5f);
  aff[c] = a1; aff[768 + c] = bb[c] - a1 * m1;
  float m2 = s2 * inv, var2 = q2 * inv - m2 * m2;
  float a2 = g[768 + c] * rsqrtf(var2 + 1e-5f);
  aff[1536 + c] = a2; aff[2304 + c] = bb[768 + c] - a2 * m2;
}
__global__ void final_kernel(const float* __restrict__ Hs, const float* __restrict__ catrelu,
                             const float* __restrict__ aff, const float* __restrict__ w_out,
                             const float* __restrict__ b_out, float* __restrict__ out) {
  __shared__ float satt[768];
  int b = blockIdx.x, c = threadIdx.x;  // 768
  const float* a_cat = aff; const float* sh_cat = aff + 768;
  const float* a_h = aff + 1536; const float* sh_h = aff + 2304;
  satt[c] = (a_h[c] * Hs[b * 768 + c] + sh_h[c]) + (a_cat[c] * catrelu[b * 768 + c] + sh_cat[c]);
  __syncthreads();
  if (c < 3) {
    float acc = b_out[c];
    for (int k = 0; k < 768; ++k) acc += satt[k] * w_out[k * 3 + c];
    out[b * 3 + c] = acc;
  }
}

// ============================================================================
extern "C" void kernel_launch(void* const* d_in, const int* in_sizes, int n_in,
                              void* d_out, int out_size, void* d_ws, size_t ws_size,
                              hipStream_t stream) {
  const float* last_h  = (const float*)d_in[0];
  const float* first_h = (const float*)d_in[1];
  const float* x_nodes = (const float*)d_in[2];
  const int*   edges   = (const int*)d_in[3];
  const int*   mask    = (const int*)d_in[4];
  const float* w_pre1  = (const float*)d_in[5];
  const float* b_pre1  = (const float*)d_in[6];
  const float* w_pre2  = (const float*)d_in[7];
  const float* b_pre2  = (const float*)d_in[8];
  const float* w_conv  = (const float*)d_in[9];
  const float* b_conv  = (const float*)d_in[10];
  const float* bng_g   = (const float*)d_in[11];
  const float* bng_b   = (const float*)d_in[12];
  const float* w_post1 = (const float*)d_in[13];
  const float* b_post1 = (const float*)d_in[14];
  const float* w_post2 = (const float*)d_in[15];
  const float* b_post2 = (const float*)d_in[16];
  const float* w_cat   = (const float*)d_in[17];
  const float* b_cat   = (const float*)d_in[18];
  const float* bn_g    = (const float*)d_in[19];
  const float* bn_b    = (const float*)d_in[20];
  const float* w_out   = (const float*)d_in[21];
  const float* b_out   = (const float*)d_in[22];
  float* out = (float*)d_out;

  const int E = in_sizes[3] / 2;  // 1048576
  const int* e_src = edges;
  const int* e_dst = edges + E;

  // ---- workspace bump allocator (total ~56 MB) ----
  char* w = (char*)d_ws;
  size_t off = 0;
  auto alloc = [&](size_t bytes) { size_t p = off; off = (off + bytes + 255) & ~(size_t)255; return p; };
  ushort16* buf0   = (ushort16*)(w + alloc((size_t)NNODES * DFEAT * 2));  // holds A0, then R2, RC, R5
  ushort16* buf1   = (ushort16*)(w + alloc((size_t)NNODES * DFEAT * 2));  // holds R1, XW, R4
  int*    csr      = (int*)(w + alloc((size_t)E * 4));
  int*    rowstart = (int*)(w + alloc((size_t)(NNODES + 1) * 4));
  int*    cursor   = (int*)(w + alloc((size_t)NNODES * 4));
  float*  disq     = (float*)(w + alloc((size_t)NNODES * 4));
  ushort16* BT     = (ushort16*)(w + alloc((size_t)DFEAT * DFEAT * 2));
  float*  biasx    = (float*)(w + alloc(DFEAT * 4));
  float*  a_aff    = (float*)(w + alloc(DFEAT * 4));
  float*  sh_aff   = (float*)(w + alloc(DFEAT * 4));
  float*  flat     = (float*)(w + alloc(64 * 768 * 4));
  float*  catrelu  = (float*)(w + alloc(64 * 768 * 4));
  float*  aff64    = (float*)(w + alloc(4 * 768 * 4));
  // zero zone (one memset): H_sent, deg counts, 5 stat sets
  size_t zoff = off;
  float* Hsent  = (float*)(w + alloc(64 * 768 * 4));
  int*   degcnt = (int*)(w + alloc((size_t)NNODES * 4));
  float* stats  = (float*)(w + alloc(5 * 2 * DFEAT * 4));
  size_t zbytes = off - zoff;

  hipMemsetAsync(w + zoff, 0, zbytes, stream);

  // ---- phase A: independent prep ----
  convert_x_kernel<<<8192, 256, 0, stream>>>(x_nodes, buf0);
  xform_w_kernel<<<DFEAT, 128, 0, stream>>>(w_pre1, b_pre1, nullptr, nullptr, BT, biasx, 300, KPAD1, DFEAT);
  sent_mean_kernel<<<dim3(64, 16), 768, 0, stream>>>(last_h, first_h, Hsent);
  deg_count_kernel<<<(E + 255) / 256, 256, 0, stream>>>(e_dst, degcnt, E);
  disq_kernel<<<NNODES / 256, 256, 0, stream>>>(degcnt, disq);
  scan_kernel<<<1, 1024, 0, stream>>>(degcnt, rowstart, cursor);
  scatter_kernel<<<(E + 255) / 256, 256, 0, stream>>>(e_src, e_dst, cursor, csr, E);

  dim3 ggrid(NNODES / BM, DFEAT / BN);
  const float invN = 1.0f / (float)NNODES;

  // ---- GEMM1: R1 = relu(x @ W1 + b1) ----
  gemm_bf16<true><<<ggrid, 256, 0, stream>>>(buf0, KPAD1, BT, KPAD1, biasx, buf1, DFEAT, KPAD1);
  stats_kernel<<<128, DFEAT, 0, stream>>>(buf1, stats + 0 * 768, 256);
  make_affine_kernel<<<1, DFEAT, 0, stream>>>(stats + 0 * 768, bng_g + 0 * DFEAT, bng_b + 0 * DFEAT, a_aff, sh_aff, invN);
  xform_w_kernel<<<DFEAT, 128, 0, stream>>>(w_pre2, b_pre2, a_aff, sh_aff, BT, biasx, DFEAT, DFEAT, DFEAT);

  // ---- GEMM2: R2 = relu(BN0(R1) @ W2 + b2) ----
  gemm_bf16<true><<<ggrid, 256, 0, stream>>>(buf1, DFEAT, BT, DFEAT, biasx, buf0, DFEAT, DFEAT);
  stats_kernel<<<128, DFEAT, 0, stream>>>(buf0, stats + 1 * 768, 256);
  make_affine_kernel<<<1, DFEAT, 0, stream>>>(stats + 1 * 768, bng_g + 1 * DFEAT, bng_b + 1 * DFEAT, a_aff, sh_aff, invN);
  xform_w_kernel<<<DFEAT, 128, 0, stream>>>(w_conv + 2 * DFEAT * DFEAT, nullptr, a_aff, sh_aff, BT, biasx, DFEAT, DFEAT, DFEAT);

  // ---- GEMM3 (no relu): XW = BN1(R2) @ Wc  (only conv i=2 survives) ----
  gemm_bf16<false><<<ggrid, 256, 0, stream>>>(buf0, DFEAT, BT, DFEAT, biasx, buf1, DFEAT, DFEAT);

  // ---- aggregation: RC = relu(D^-1/2 (A+I) D^-1/2 XW + b_conv[2]) ----
  aggregate_kernel<<<NNODES, 192, 0, stream>>>((const uint32*)buf1, csr, rowstart, disq, b_conv + 2 * DFEAT, (uint32*)buf0);
  stats_kernel<<<128, DFEAT, 0, stream>>>(buf0, stats + 2 * 768, 256);
  make_affine_kernel<<<1, DFEAT, 0, stream>>>(stats + 2 * 768, bng_g + 4 * DFEAT, bng_b + 4 * DFEAT, a_aff, sh_aff, invN);
  xform_w_kernel<<<DFEAT, 128, 0, stream>>>(w_post1, b_post1, a_aff, sh_aff, BT, biasx, DFEAT, DFEAT, DFEAT);

  // ---- GEMM4: R4 = relu(BN4(RC) @ Wp1 + bp1) ----
  gemm_bf16<true><<<ggrid, 256, 0, stream>>>(buf0, DFEAT, BT, DFEAT, biasx, buf1, DFEAT, DFEAT);
  stats_kernel<<<128, DFEAT, 0, stream>>>(buf1, stats + 3 * 768, 256);
  make_affine_kernel<<<1, DFEAT, 0, stream>>>(stats + 3 * 768, bng_g + 5 * DFEAT, bng_b + 5 * DFEAT, a_aff, sh_aff, invN);
  xform_w_kernel<<<DFEAT, 128, 0, stream>>>(w_post2, b_post2, a_aff, sh_aff, BT, biasx, DFEAT, DFEAT, DFEAT);

  // ---- GEMM5: R5 = relu(BN5(R4) @ Wp2 + bp2) ----
  gemm_bf16<true><<<ggrid, 256, 0, stream>>>(buf1, DFEAT, BT, DFEAT, biasx, buf0, DFEAT, DFEAT);
  stats_kernel<<<128, DFEAT, 0, stream>>>(buf0, stats + 4 * 768, 256);
  make_affine_kernel<<<1, DFEAT, 0, stream>>>(stats + 4 * 768, bng_g + 6 * DFEAT, bng_b + 6 * DFEAT, a_aff, sh_aff, invN);

  // ---- gather masked nodes (BN6 fused) + tail ----
  gather_kernel<<<64, DFEAT, 0, stream>>>(mask, buf0, a_aff, sh_aff, flat);
  cat_gemm_kernel<<<64, 256, 0, stream>>>(flat, w_cat, b_cat, catrelu);
  stats64_kernel<<<1, 768, 0, stream>>>(catrelu, Hsent, bn_g, bn_b, aff64);
  final_kernel<<<64, 768, 0, stream>>>(Hsent, catrelu, aff64, w_out, b_out, out);
}

// Round 2
// 1082.113 us; speedup vs baseline: 1.1189x; 1.1189x over previous
//
#include <hip/hip_runtime.h>

typedef unsigned int uint32;
typedef unsigned short ushort16;

typedef __attribute__((ext_vector_type(8))) short bf16x8;
typedef __attribute__((ext_vector_type(4))) float f32x4;

#define NNODES 32768
#define DFEAT 384
#define KPAD1 320

__device__ __forceinline__ float bf2f(ushort16 u) {
  union { uint32 i; float f; } x; x.i = ((uint32)u) << 16; return x.f;
}
__device__ __forceinline__ float bflo(uint32 v) {
  union { uint32 i; float f; } x; x.i = v << 16; return x.f;
}
__device__ __forceinline__ float bfhi(uint32 v) {
  union { uint32 i; float f; } x; x.i = v & 0xffff0000u; return x.f;
}
__device__ __forceinline__ ushort16 f2bf(float f) {
  union { float f; uint32 i; } x; x.f = f;
  uint32 r = (x.i + 0x7fffu + ((x.i >> 16) & 1u)) >> 16;
  return (ushort16)r;
}

// ---------------- x_nodes f32 [32768,300] -> bf16 [32768,320] (zero-padded) --
__global__ void convert_x_kernel(const float* __restrict__ X, ushort16* __restrict__ A0) {
  const int total = NNODES * KPAD1;
  for (int idx = blockIdx.x * blockDim.x + threadIdx.x; idx < total;
       idx += gridDim.x * blockDim.x) {
    int row = idx / KPAD1, col = idx - row * KPAD1;
    float v = (col < 300) ? X[(size_t)row * 300 + col] : 0.f;
    A0[idx] = f2bf(v);
  }
}

// ---------------- sentence mean partials: Hpart[sc][b][768], no atomics -----
__global__ void sent_mean_kernel(const float* __restrict__ last,
                                 const float* __restrict__ first,
                                 float* __restrict__ Hpart) {
  int b = blockIdx.x, sc = blockIdx.y, e = threadIdx.x;  // block 768, grid (64,16)
  int s0 = sc * 32;
  const float* pl = last + ((size_t)b * 512 + s0) * 768 + e;
  const float* pf = first + ((size_t)b * 512 + s0) * 768 + e;
  float a0 = 0.f, a1 = 0.f, a2 = 0.f, a3 = 0.f;
  for (int i = 0; i < 32; i += 4) {
    a0 += pl[(i + 0) * 768] + pf[(i + 0) * 768];
    a1 += pl[(i + 1) * 768] + pf[(i + 1) * 768];
    a2 += pl[(i + 2) * 768] + pf[(i + 2) * 768];
    a3 += pl[(i + 3) * 768] + pf[(i + 3) * 768];
  }
  Hpart[((size_t)sc * 64 + b) * 768 + e] = a0 + a1 + a2 + a3;
}

// ---------------- degree / CSR build ----------------------------------------
__global__ void deg_count_kernel(const int* __restrict__ dst, int* __restrict__ cnt, int E) {
  int e = blockIdx.x * blockDim.x + threadIdx.x;
  if (e < E) atomicAdd(&cnt[dst[e]], 1);
}
__global__ void disq_kernel(const int* __restrict__ cnt, float* __restrict__ disq) {
  int n = blockIdx.x * blockDim.x + threadIdx.x;
  if (n < NNODES) disq[n] = rsqrtf((float)cnt[n] + 1.0f);  // +1 self loop
}
__global__ void scan_kernel(const int* __restrict__ cnt, int* __restrict__ row_start,
                            int* __restrict__ cursor) {
  __shared__ int buf[1024];
  int t = threadIdx.x;
  int base = t * 32;
  int s = 0;
  for (int i = 0; i < 32; ++i) s += cnt[base + i];
  buf[t] = s; __syncthreads();
  int x = s;
  for (int off = 1; off < 1024; off <<= 1) {
    int v = (t >= off) ? buf[t - off] : 0;
    __syncthreads();
    x += v; buf[t] = x;
    __syncthreads();
  }
  int run = x - s;
  for (int i = 0; i < 32; ++i) {
    row_start[base + i] = run; cursor[base + i] = run;
    run += cnt[base + i];
  }
  if (t == 1023) row_start[NNODES] = run;
}
__global__ void scatter_kernel(const int* __restrict__ src, const int* __restrict__ dst,
                               int* __restrict__ cursor, int* __restrict__ csr, int E) {
  int e = blockIdx.x * blockDim.x + threadIdx.x;
  if (e < E) {
    int d = dst[e];
    int pos = atomicAdd(&cursor[d], 1);
    csr[pos] = src[e];
  }
}

// ---------------- weight transform with inline BN-affine from spread stats --
// BT[n][k] = a_k*W[k][n] bf16;  bias_out[n] = bias[n] + sum_k sh_k*W[k][n]
__global__ void xform_w_kernel(const float* __restrict__ W, const float* __restrict__ bias,
                               const float* __restrict__ stat, const float* __restrict__ g,
                               const float* __restrict__ bb, float invN,
                               ushort16* __restrict__ BT, float* __restrict__ bias_out,
                               int K, int Kpad, int Nw) {
  __shared__ float red[128];
  int n = blockIdx.x, t = threadIdx.x;
  float part = 0.f;
  for (int k = t; k < Kpad; k += 128) {
    ushort16 o = 0; float contrib = 0.f;
    if (k < K) {
      float ak = 1.f, shk = 0.f;
      if (stat) {
        float s = 0.f, q = 0.f;
        for (int i = 0; i < 8; ++i) { s += stat[k * 8 + i]; q += stat[(DFEAT + k) * 8 + i]; }
        float mean = s * invN, var = q * invN - mean * mean;
        ak = g[k] * rsqrtf(var + 1e-5f);
        shk = bb[k] - ak * mean;
      }
      float w = W[(size_t)k * Nw + n];
      o = f2bf(ak * w);
      contrib = shk * w;
    }
    BT[(size_t)n * Kpad + k] = o;
    part += contrib;
  }
  red[t] = part; __syncthreads();
  for (int off = 64; off > 0; off >>= 1) {
    if (t < off) red[t] += red[t + off];
    __syncthreads();
  }
  if (t == 0) bias_out[n] = (bias ? bias[n] : 0.f) + red[0];
}

// ---------------- MFMA bf16 GEMM with fused stats / row-scale ---------------
#define BM 128
#define BN 128
#define BKT 32
#define LDT 40  // BKT + 8 pad shorts

template <bool RELU, bool STATS, bool RSCALE>
__global__ __launch_bounds__(256) void gemm_bf16(
    const ushort16* __restrict__ A, int lda, const ushort16* __restrict__ BT, int ldb,
    const float* __restrict__ bias, const float* __restrict__ rowscale,
    ushort16* __restrict__ C, int Ntot, int K, float* __restrict__ stat) {
  __shared__ __attribute__((aligned(16))) ushort16 As[BM * LDT];
  __shared__ __attribute__((aligned(16))) ushort16 Bs[BN * LDT];
  __shared__ float ssum[BN], ssq[BN];
  int bm0 = blockIdx.x * BM, bn0 = blockIdx.y * BN;
  int tid = threadIdx.x;
  if (STATS) {
    if (tid < BN) { ssum[tid] = 0.f; ssq[tid] = 0.f; }
  }
  int lane = tid & 63, wave = tid >> 6;
  int wm = (wave & 1) * 64, wn = (wave >> 1) * 64;
  int l15 = lane & 15, quad = lane >> 4;

  f32x4 acc[4][4];
  for (int i = 0; i < 4; ++i)
    for (int j = 0; j < 4; ++j) acc[i][j] = (f32x4)0.f;

  for (int kk = 0; kk < K; kk += BKT) {
    __syncthreads();
    for (int i = 0; i < 2; ++i) {
      int chunk = tid + i * 256;
      int row = chunk >> 2, cc = chunk & 3;
      uint4 va = *(const uint4*)(A + (size_t)(bm0 + row) * lda + kk + cc * 8);
      *(uint4*)(&As[row * LDT + cc * 8]) = va;
      uint4 vb = *(const uint4*)(BT + (size_t)(bn0 + row) * ldb + kk + cc * 8);
      *(uint4*)(&Bs[row * LDT + cc * 8]) = vb;
    }
    __syncthreads();
    bf16x8 af[4], bfr[4];
    for (int mi = 0; mi < 4; ++mi)
      af[mi] = *(const bf16x8*)(&As[(wm + mi * 16 + l15) * LDT + quad * 8]);
    for (int ni = 0; ni < 4; ++ni)
      bfr[ni] = *(const bf16x8*)(&Bs[(wn + ni * 16 + l15) * LDT + quad * 8]);
    for (int mi = 0; mi < 4; ++mi)
      for (int ni = 0; ni < 4; ++ni)
        acc[mi][ni] = __builtin_amdgcn_mfma_f32_16x16x32_bf16(af[mi], bfr[ni], acc[mi][ni], 0, 0, 0);
  }
  // epilogue: C/D layout col=lane&15, row=quad*4+reg
  for (int ni = 0; ni < 4; ++ni) {
    int coll = wn + ni * 16 + l15;
    int col = bn0 + coll;
    float bv = bias[col];
    float s = 0.f, q = 0.f;
    for (int mi = 0; mi < 4; ++mi) {
      for (int r = 0; r < 4; ++r) {
        int row = bm0 + wm + mi * 16 + quad * 4 + r;
        float v = acc[mi][ni][r] + bv;
        if (RELU) v = fmaxf(v, 0.f);
        if (RSCALE) v *= rowscale[row];
        C[(size_t)row * Ntot + col] = f2bf(v);
        if (STATS) { s += v; q += v * v; }
      }
    }
    if (STATS) { atomicAdd(&ssum[coll], s); atomicAdd(&ssq[coll], q); }
  }
  if (STATS) {
    __syncthreads();
    int sp = blockIdx.x & 7;
    if (tid < BN) {
      atomicAdd(&stat[(bn0 + tid) * 8 + sp], ssum[tid]);
      atomicAdd(&stat[(DFEAT + bn0 + tid) * 8 + sp], ssq[tid]);
    }
  }
}

// ---------------- chunked, XCD-affine GCN aggregation -----------------------
// XWs rows prescaled by disq: RC[n] = relu(disq[n] * (XWs[n] + sum_s XWs[s]) + b)
// 6 chunks of 64 cols (=128B line each, 4MB working set = 1 XCD L2).
// slot = blockIdx%8 -> chunk via map; slots 6,7 take node-halves of chunks 0,3.
__global__ __launch_bounds__(256) void aggregate_kernel(
    const uint32* __restrict__ XWs, const int* __restrict__ csr,
    const int* __restrict__ row_start, const float* __restrict__ disq,
    const float* __restrict__ bconv, uint32* __restrict__ RC2,
    float* __restrict__ stat) {
  int bx = blockIdx.x;
  int slot = bx & 7, g = bx >> 3;
  int chunk = slot < 6 ? slot : (slot == 6 ? 0 : 3);
  int noff = slot < 6 ? 0 : 16384;
  int ngrp = (slot == 0 || slot == 3 || slot >= 6) ? 512 : 1024;
  if (g >= ngrp) return;
  __shared__ float ssum[64], ssq[64];
  int tid = threadIdx.x;
  if (tid < 64) { ssum[tid] = 0.f; ssq[tid] = 0.f; }
  __syncthreads();
  int lane = tid & 63, wave = tid >> 6;
  int half = lane >> 5, cl = lane & 31;
  int cbase = chunk * 32;  // uint32 offset within 192-uint32 row
  float b0 = bconv[chunk * 64 + 2 * cl], b1 = bconv[chunk * 64 + 2 * cl + 1];
  float ls0 = 0.f, ls1 = 0.f, lq0 = 0.f, lq1 = 0.f;
  int nodebase = noff + (g * 4 + wave) * 8;
  for (int ni = 0; ni < 8; ++ni) {
    int n = nodebase + ni;
    int beg = row_start[n], end = row_start[n + 1];
    int deg = end - beg;
    int len0 = (deg + 1) >> 1;
    int myBeg = beg + (half ? len0 : 0);
    int myLen = half ? (deg - len0) : len0;
    float a0, a1;
    if (half == 0) {
      uint32 v = XWs[(size_t)n * 192 + cbase + cl];
      a0 = bflo(v); a1 = bfhi(v);
    } else { a0 = 0.f; a1 = 0.f; }
    for (int bb0 = 0; bb0 < len0; bb0 += 32) {
      int rem = myLen - bb0;
      int idx = (cl < rem) ? csr[myBeg + bb0 + cl] : -1;
      int jmax = min(32, len0 - bb0);  // uniform across wave (len0 >= len1)
      for (int j = 0; j < jmax; ++j) {
        int s = __shfl(idx, (half << 5) + j, 64);
        if (s >= 0) {
          uint32 v = XWs[(size_t)s * 192 + cbase + cl];
          a0 += bflo(v); a1 += bfhi(v);
        }
      }
    }
    a0 += __shfl_xor(a0, 32, 64);
    a1 += __shfl_xor(a1, 32, 64);
    if (half == 0) {
      float din = disq[n];
      a0 = fmaxf(din * a0 + b0, 0.f);
      a1 = fmaxf(din * a1 + b1, 0.f);
      RC2[(size_t)n * 192 + cbase + cl] = (uint32)f2bf(a0) | ((uint32)f2bf(a1) << 16);
      ls0 += a0; lq0 += a0 * a0; ls1 += a1; lq1 += a1 * a1;
    }
  }
  if (half == 0) {
    atomicAdd(&ssum[2 * cl], ls0); atomicAdd(&ssum[2 * cl + 1], ls1);
    atomicAdd(&ssq[2 * cl], lq0);  atomicAdd(&ssq[2 * cl + 1], lq1);
  }
  __syncthreads();
  if (tid < 64) {
    int col = chunk * 64 + tid;
    int sp = g & 7;
    atomicAdd(&stat[col * 8 + sp], ssum[tid]);
    atomicAdd(&stat[(DFEAT + col) * 8 + sp], ssq[tid]);
  }
}

// ---------------- gather 2 masked nodes/sample + inline BN6 -> flat f32 -----
__global__ void gather_kernel(const int* __restrict__ mask, const ushort16* __restrict__ R5,
                              const float* __restrict__ stat, const float* __restrict__ g,
                              const float* __restrict__ bb, float invN,
                              float* __restrict__ flat) {
  __shared__ int smin, smax;
  int b = blockIdx.x, t = threadIdx.x;  // 384
  if (t == 0) { smin = 1 << 30; smax = -1; }
  __syncthreads();
  for (int p = t; p < 512; p += 384)
    if (mask[b * 512 + p]) { atomicMin(&smin, p); atomicMax(&smax, p); }
  __syncthreads();
  float s = 0.f, q = 0.f;
  for (int i = 0; i < 8; ++i) { s += stat[t * 8 + i]; q += stat[(DFEAT + t) * 8 + i]; }
  float mean = s * invN, var = q * invN - mean * mean;
  float a = g[t] * rsqrtf(var + 1e-5f), sh = bb[t] - a * mean;
  int sel[2] = {smin, smax};
  for (int j = 0; j < 2; ++j) {
    float v = bf2f(R5[(size_t)(b * 512 + sel[j]) * DFEAT + t]);
    flat[(size_t)b * 768 + j * DFEAT + t] = a * v + sh;
  }
}

// ---------------- tail ------------------------------------------------------
__global__ void cat_gemm_kernel(const float* __restrict__ flat, const float* __restrict__ Wc,
                                const float* __restrict__ bc, float* __restrict__ out) {
  __shared__ float arow[768];
  int b = blockIdx.x, t = threadIdx.x;  // 256
  for (int k = t; k < 768; k += 256) arow[k] = flat[b * 768 + k];
  __syncthreads();
  for (int j = t; j < 768; j += 256) {
    float acc = bc[j];
    for (int k = 0; k < 768; ++k) acc += arow[k] * Wc[(size_t)k * 768 + j];
    out[b * 768 + j] = fmaxf(acc, 0.f);
  }
}
// folds Hpart -> Hsent, computes both batch-BN affines
__global__ void stats64_kernel(const float* __restrict__ catrelu, const float* __restrict__ Hpart,
                               float* __restrict__ Hsent,
                               const float* __restrict__ g, const float* __restrict__ bb,
                               float* __restrict__ aff) {
  int c = threadIdx.x;  // 768
  float s1 = 0, q1 = 0, s2 = 0, q2 = 0;
  for (int b = 0; b < 64; ++b) {
    float v = catrelu[b * 768 + c]; s1 += v; q1 += v * v;
    float h = 0.f;
    for (int sc = 0; sc < 16; ++sc) h += Hpart[((size_t)sc * 64 + b) * 768 + c];
    h *= (0.5f / 512.f);
    Hsent[b * 768 + c] = h;
    s2 += h; q2 += h * h;
  }
  const float inv = 1.0f / 64.0f;
  float m1 = s1 * inv, var1 = q1 * inv - m1 * m1;
  float a1 = g[c] * rsqrtf(var1 + 1e-5f);
  aff[c] = a1; aff[768 + c] = bb[c] - a1 * m1;
  float m2 = s2 * inv, var2 = q2 * inv - m2 * m2;
  float a2 = g[768 + c] * rsqrtf(var2 + 1e-5f);
  aff[1536 + c] = a2; aff[2304 + c] = bb[768 + c] - a2 * m2;
}
__global__ void final_kernel(const float* __restrict__ Hs, const float* __restrict__ catrelu,
                             const float* __restrict__ aff, const float* __restrict__ w_out,
                             const float* __restrict__ b_out, float* __restrict__ out) {
  __shared__ float red[12];
  int b = blockIdx.x, t = threadIdx.x;  // 256
  float p0 = 0, p1 = 0, p2 = 0;
  for (int k = t; k < 768; k += 256) {
    float att = (aff[1536 + k] * Hs[b * 768 + k] + aff[2304 + k]) +
                (aff[k] * catrelu[b * 768 + k] + aff[768 + k]);
    p0 += att * w_out[k * 3 + 0];
    p1 += att * w_out[k * 3 + 1];
    p2 += att * w_out[k * 3 + 2];
  }
  for (int off = 32; off > 0; off >>= 1) {
    p0 += __shfl_down(p0, off, 64);
    p1 += __shfl_down(p1, off, 64);
    p2 += __shfl_down(p2, off, 64);
  }
  int wv = t >> 6;
  if ((t & 63) == 0) { red[wv * 3 + 0] = p0; red[wv * 3 + 1] = p1; red[wv * 3 + 2] = p2; }
  __syncthreads();
  if (t == 0) {
    out[b * 3 + 0] = b_out[0] + red[0] + red[3] + red[6] + red[9];
    out[b * 3 + 1] = b_out[1] + red[1] + red[4] + red[7] + red[10];
    out[b * 3 + 2] = b_out[2] + red[2] + red[5] + red[8] + red[11];
  }
}

// ============================================================================
extern "C" void kernel_launch(void* const* d_in, const int* in_sizes, int n_in,
                              void* d_out, int out_size, void* d_ws, size_t ws_size,
                              hipStream_t stream) {
  const float* last_h  = (const float*)d_in[0];
  const float* first_h = (const float*)d_in[1];
  const float* x_nodes = (const float*)d_in[2];
  const int*   edges   = (const int*)d_in[3];
  const int*   mask    = (const int*)d_in[4];
  const float* w_pre1  = (const float*)d_in[5];
  const float* b_pre1  = (const float*)d_in[6];
  const float* w_pre2  = (const float*)d_in[7];
  const float* b_pre2  = (const float*)d_in[8];
  const float* w_conv  = (const float*)d_in[9];
  const float* b_conv  = (const float*)d_in[10];
  const float* bng_g   = (const float*)d_in[11];
  const float* bng_b   = (const float*)d_in[12];
  const float* w_post1 = (const float*)d_in[13];
  const float* b_post1 = (const float*)d_in[14];
  const float* w_post2 = (const float*)d_in[15];
  const float* b_post2 = (const float*)d_in[16];
  const float* w_cat   = (const float*)d_in[17];
  const float* b_cat   = (const float*)d_in[18];
  const float* bn_g    = (const float*)d_in[19];
  const float* bn_b    = (const float*)d_in[20];
  const float* w_out   = (const float*)d_in[21];
  const float* b_out   = (const float*)d_in[22];
  float* out = (float*)d_out;

  const int E = in_sizes[3] / 2;  // 1048576
  const int* e_src = edges;
  const int* e_dst = edges + E;

  char* w = (char*)d_ws;
  size_t off = 0;
  auto alloc = [&](size_t bytes) { size_t p = off; off = (off + bytes + 255) & ~(size_t)255; return p; };
  ushort16* buf0   = (ushort16*)(w + alloc((size_t)NNODES * DFEAT * 2));  // A0, R2, RC, R5
  ushort16* buf1   = (ushort16*)(w + alloc((size_t)NNODES * DFEAT * 2));  // R1, XW', R4
  int*    csr      = (int*)(w + alloc((size_t)E * 4));
  int*    rowstart = (int*)(w + alloc((size_t)(NNODES + 1) * 4));
  int*    cursor   = (int*)(w + alloc((size_t)NNODES * 4));
  float*  disq     = (float*)(w + alloc((size_t)NNODES * 4));
  ushort16* BT     = (ushort16*)(w + alloc((size_t)DFEAT * DFEAT * 2));
  float*  biasx    = (float*)(w + alloc(DFEAT * 4));
  float*  flat     = (float*)(w + alloc(64 * 768 * 4));
  float*  catrelu  = (float*)(w + alloc(64 * 768 * 4));
  float*  aff64    = (float*)(w + alloc(4 * 768 * 4));
  float*  Hpart    = (float*)(w + alloc((size_t)16 * 64 * 768 * 4));
  float*  Hsent    = (float*)(w + alloc(64 * 768 * 4));
  // zero zone: deg counts + 5 spread-stat sets
  size_t zoff = off;
  int*   degcnt = (int*)(w + alloc((size_t)NNODES * 4));
  float* stats  = (float*)(w + alloc((size_t)5 * 768 * 8 * 4));
  size_t zbytes = off - zoff;

  hipMemsetAsync(w + zoff, 0, zbytes, stream);

  const float invN = 1.0f / (float)NNODES;
  float* st0 = stats + 0 * 768 * 8;  // BN0 (after GEMM1)
  float* st1 = stats + 1 * 768 * 8;  // BN1 (after GEMM2)
  float* st2 = stats + 2 * 768 * 8;  // BN4 (after aggregate)
  float* st3 = stats + 3 * 768 * 8;  // BN5 (after GEMM4)
  float* st4 = stats + 4 * 768 * 8;  // BN6 (after GEMM5)

  // ---- phase A: independent prep ----
  convert_x_kernel<<<8192, 256, 0, stream>>>(x_nodes, buf0);
  xform_w_kernel<<<DFEAT, 128, 0, stream>>>(w_pre1, b_pre1, nullptr, nullptr, nullptr, invN, BT, biasx, 300, KPAD1, DFEAT);
  sent_mean_kernel<<<dim3(64, 16), 768, 0, stream>>>(last_h, first_h, Hpart);
  deg_count_kernel<<<(E + 255) / 256, 256, 0, stream>>>(e_dst, degcnt, E);
  disq_kernel<<<NNODES / 256, 256, 0, stream>>>(degcnt, disq);
  scan_kernel<<<1, 1024, 0, stream>>>(degcnt, rowstart, cursor);
  scatter_kernel<<<(E + 255) / 256, 256, 0, stream>>>(e_src, e_dst, cursor, csr, E);

  dim3 ggrid(NNODES / BM, DFEAT / BN);

  // ---- GEMM1: R1 = relu(x @ W1 + b1), stats->BN0 ----
  gemm_bf16<true, true, false><<<ggrid, 256, 0, stream>>>(buf0, KPAD1, BT, KPAD1, biasx, nullptr, buf1, DFEAT, KPAD1, st0);
  xform_w_kernel<<<DFEAT, 128, 0, stream>>>(w_pre2, b_pre2, st0, bng_g + 0 * DFEAT, bng_b + 0 * DFEAT, invN, BT, biasx, DFEAT, DFEAT, DFEAT);

  // ---- GEMM2: R2 = relu(BN0(R1) @ W2 + b2), stats->BN1 ----
  gemm_bf16<true, true, false><<<ggrid, 256, 0, stream>>>(buf1, DFEAT, BT, DFEAT, biasx, nullptr, buf0, DFEAT, DFEAT, st1);
  xform_w_kernel<<<DFEAT, 128, 0, stream>>>(w_conv + 2 * DFEAT * DFEAT, nullptr, st1, bng_g + 1 * DFEAT, bng_b + 1 * DFEAT, invN, BT, biasx, DFEAT, DFEAT, DFEAT);

  // ---- GEMM3: XW' = disq[row] * (BN1(R2) @ Wc)  (conv i=2 only survives) ----
  gemm_bf16<false, false, true><<<ggrid, 256, 0, stream>>>(buf0, DFEAT, BT, DFEAT, biasx, disq, buf1, DFEAT, DFEAT, nullptr);

  // ---- aggregation (chunked, XCD-affine), stats->BN4 ----
  aggregate_kernel<<<8192, 256, 0, stream>>>((const uint32*)buf1, csr, rowstart, disq, b_conv + 2 * DFEAT, (uint32*)buf0, st2);
  xform_w_kernel<<<DFEAT, 128, 0, stream>>>(w_post1, b_post1, st2, bng_g + 4 * DFEAT, bng_b + 4 * DFEAT, invN, BT, biasx, DFEAT, DFEAT, DFEAT);

  // ---- GEMM4: R4 = relu(BN4(RC) @ Wp1 + bp1), stats->BN5 ----
  gemm_bf16<true, true, false><<<ggrid, 256, 0, stream>>>(buf0, DFEAT, BT, DFEAT, biasx, nullptr, buf1, DFEAT, DFEAT, st3);
  xform_w_kernel<<<DFEAT, 128, 0, stream>>>(w_post2, b_post2, st3, bng_g + 5 * DFEAT, bng_b + 5 * DFEAT, invN, BT, biasx, DFEAT, DFEAT, DFEAT);

  // ---- GEMM5: R5 = relu(BN5(R4) @ Wp2 + bp2), stats->BN6 ----
  gemm_bf16<true, true, false><<<ggrid, 256, 0, stream>>>(buf1, DFEAT, BT, DFEAT, biasx, nullptr, buf0, DFEAT, DFEAT, st4);

  // ---- gather (BN6 inline) + tail ----
  gather_kernel<<<64, DFEAT, 0, stream>>>(mask, buf0, st4, bng_g + 6 * DFEAT, bng_b + 6 * DFEAT, invN, flat);
  cat_gemm_kernel<<<64, 256, 0, stream>>>(flat, w_cat, b_cat, catrelu);
  stats64_kernel<<<1, 768, 0, stream>>>(catrelu, Hpart, Hsent, bn_g, bn_b, aff64);
  final_kernel<<<64, 256, 0, stream>>>(Hsent, catrelu, aff64, w_out, b_out, out);
}

// Round 3
// 909.995 us; speedup vs baseline: 1.3305x; 1.1891x over previous
//
#include <hip/hip_runtime.h>

typedef unsigned int uint32;
typedef unsigned short ushort16;

typedef __attribute__((ext_vector_type(8))) short bf16x8;
typedef __attribute__((ext_vector_type(4))) float f32x4;

#define NNODES 32768
#define DFEAT 384
#define KPAD1 320

__device__ __forceinline__ float bf2f(ushort16 u) {
  union { uint32 i; float f; } x; x.i = ((uint32)u) << 16; return x.f;
}
__device__ __forceinline__ float bflo(uint32 v) {
  union { uint32 i; float f; } x; x.i = v << 16; return x.f;
}
__device__ __forceinline__ float bfhi(uint32 v) {
  union { uint32 i; float f; } x; x.i = v & 0xffff0000u; return x.f;
}
__device__ __forceinline__ ushort16 f2bf(float f) {
  union { float f; uint32 i; } x; x.f = f;
  uint32 r = (x.i + 0x7fffu + ((x.i >> 16) & 1u)) >> 16;
  return (ushort16)r;
}

// ---------------- x_nodes f32 [32768,300] -> bf16 [32768,320], no int div ---
__global__ void convert_x_kernel(const float* __restrict__ X, ushort16* __restrict__ A0) {
  int row = blockIdx.x * 4 + (threadIdx.x >> 6);
  int lane = threadIdx.x & 63;
  const float* xr = X + (size_t)row * 300;
  ushort16* ar = A0 + (size_t)row * KPAD1;
#pragma unroll
  for (int i = 0; i < 5; ++i) {
    int col = lane + i * 64;
    float v = (col < 300) ? xr[col] : 0.f;
    ar[col] = f2bf(v);
  }
}

// ---------------- sentence mean partials: Hpart[sc][b][768], no atomics -----
__global__ void sent_mean_kernel(const float* __restrict__ last,
                                 const float* __restrict__ first,
                                 float* __restrict__ Hpart) {
  int b = blockIdx.x, sc = blockIdx.y, e = threadIdx.x;  // block 768, grid (64,16)
  int s0 = sc * 32;
  const float* pl = last + ((size_t)b * 512 + s0) * 768 + e;
  const float* pf = first + ((size_t)b * 512 + s0) * 768 + e;
  float a0 = 0.f, a1 = 0.f, a2 = 0.f, a3 = 0.f;
  for (int i = 0; i < 32; i += 4) {
    a0 += pl[(i + 0) * 768] + pf[(i + 0) * 768];
    a1 += pl[(i + 1) * 768] + pf[(i + 1) * 768];
    a2 += pl[(i + 2) * 768] + pf[(i + 2) * 768];
    a3 += pl[(i + 3) * 768] + pf[(i + 3) * 768];
  }
  Hpart[((size_t)sc * 64 + b) * 768 + e] = a0 + a1 + a2 + a3;
}
// fold partials -> Hsent [64,768]
__global__ void hsent_kernel(const float* __restrict__ Hpart, float* __restrict__ Hsent) {
  int b = blockIdx.x, e = threadIdx.x;  // 64 blocks x 768
  float h = 0.f;
#pragma unroll
  for (int sc = 0; sc < 16; ++sc) h += Hpart[((size_t)sc * 64 + b) * 768 + e];
  Hsent[(size_t)b * 768 + e] = h * (0.5f / 512.f);
}

// ---------------- degree / CSR build ----------------------------------------
__global__ void deg_count_kernel(const int* __restrict__ dst, int* __restrict__ cnt, int E) {
  int e = blockIdx.x * blockDim.x + threadIdx.x;
  if (e < E) atomicAdd(&cnt[dst[e]], 1);
}
__global__ void disq_kernel(const int* __restrict__ cnt, float* __restrict__ disq) {
  int n = blockIdx.x * blockDim.x + threadIdx.x;
  if (n < NNODES) disq[n] = rsqrtf((float)cnt[n] + 1.0f);  // +1 self loop
}
__global__ void scan_kernel(const int* __restrict__ cnt, int* __restrict__ row_start,
                            int* __restrict__ cursor) {
  __shared__ int buf[1024];
  int t = threadIdx.x;
  int base = t * 32;
  int s = 0;
  for (int i = 0; i < 32; ++i) s += cnt[base + i];
  buf[t] = s; __syncthreads();
  int x = s;
  for (int off = 1; off < 1024; off <<= 1) {
    int v = (t >= off) ? buf[t - off] : 0;
    __syncthreads();
    x += v; buf[t] = x;
    __syncthreads();
  }
  int run = x - s;
  for (int i = 0; i < 32; ++i) {
    row_start[base + i] = run; cursor[base + i] = run;
    run += cnt[base + i];
  }
  if (t == 1023) row_start[NNODES] = run;
}
__global__ void scatter_kernel(const int* __restrict__ src, const int* __restrict__ dst,
                               int* __restrict__ cursor, int* __restrict__ csr, int E) {
  int e = blockIdx.x * blockDim.x + threadIdx.x;
  if (e < E) {
    int d = dst[e];
    int pos = atomicAdd(&cursor[d], 1);
    csr[pos] = src[e];
  }
}

// ---------------- weight transform with inline BN-affine from spread stats --
__global__ void xform_w_kernel(const float* __restrict__ W, const float* __restrict__ bias,
                               const float* __restrict__ stat, const float* __restrict__ g,
                               const float* __restrict__ bb, float invN,
                               ushort16* __restrict__ BT, float* __restrict__ bias_out,
                               int K, int Kpad, int Nw) {
  __shared__ float red[128];
  int n = blockIdx.x, t = threadIdx.x;
  float part = 0.f;
  for (int k = t; k < Kpad; k += 128) {
    ushort16 o = 0; float contrib = 0.f;
    if (k < K) {
      float ak = 1.f, shk = 0.f;
      if (stat) {
        float s = 0.f, q = 0.f;
        for (int i = 0; i < 8; ++i) { s += stat[k * 8 + i]; q += stat[(DFEAT + k) * 8 + i]; }
        float mean = s * invN, var = q * invN - mean * mean;
        ak = g[k] * rsqrtf(var + 1e-5f);
        shk = bb[k] - ak * mean;
      }
      float w = W[(size_t)k * Nw + n];
      o = f2bf(ak * w);
      contrib = shk * w;
    }
    BT[(size_t)n * Kpad + k] = o;
    part += contrib;
  }
  red[t] = part; __syncthreads();
  for (int off = 64; off > 0; off >>= 1) {
    if (t < off) red[t] += red[t + off];
    __syncthreads();
  }
  if (t == 0) bias_out[n] = (bias ? bias[n] : 0.f) + red[0];
}

// ---------------- MFMA bf16 GEMM with fused stats / row-scale ---------------
#define BM 128
#define BN 128
#define BKT 32
#define LDT 40  // BKT + 8 pad shorts

template <bool RELU, bool STATS, bool RSCALE>
__global__ __launch_bounds__(256) void gemm_bf16(
    const ushort16* __restrict__ A, int lda, const ushort16* __restrict__ BT, int ldb,
    const float* __restrict__ bias, const float* __restrict__ rowscale,
    ushort16* __restrict__ C, int Ntot, int K, float* __restrict__ stat) {
  __shared__ __attribute__((aligned(16))) ushort16 As[BM * LDT];
  __shared__ __attribute__((aligned(16))) ushort16 Bs[BN * LDT];
  __shared__ float ssum[BN], ssq[BN];
  int bm0 = blockIdx.x * BM, bn0 = blockIdx.y * BN;
  int tid = threadIdx.x;
  if (STATS) {
    if (tid < BN) { ssum[tid] = 0.f; ssq[tid] = 0.f; }
  }
  int lane = tid & 63, wave = tid >> 6;
  int wm = (wave & 1) * 64, wn = (wave >> 1) * 64;
  int l15 = lane & 15, quad = lane >> 4;

  f32x4 acc[4][4];
  for (int i = 0; i < 4; ++i)
    for (int j = 0; j < 4; ++j) acc[i][j] = (f32x4)0.f;

  for (int kk = 0; kk < K; kk += BKT) {
    __syncthreads();
    for (int i = 0; i < 2; ++i) {
      int chunk = tid + i * 256;
      int row = chunk >> 2, cc = chunk & 3;
      uint4 va = *(const uint4*)(A + (size_t)(bm0 + row) * lda + kk + cc * 8);
      *(uint4*)(&As[row * LDT + cc * 8]) = va;
      uint4 vb = *(const uint4*)(BT + (size_t)(bn0 + row) * ldb + kk + cc * 8);
      *(uint4*)(&Bs[row * LDT + cc * 8]) = vb;
    }
    __syncthreads();
    bf16x8 af[4], bfr[4];
    for (int mi = 0; mi < 4; ++mi)
      af[mi] = *(const bf16x8*)(&As[(wm + mi * 16 + l15) * LDT + quad * 8]);
    for (int ni = 0; ni < 4; ++ni)
      bfr[ni] = *(const bf16x8*)(&Bs[(wn + ni * 16 + l15) * LDT + quad * 8]);
    for (int mi = 0; mi < 4; ++mi)
      for (int ni = 0; ni < 4; ++ni)
        acc[mi][ni] = __builtin_amdgcn_mfma_f32_16x16x32_bf16(af[mi], bfr[ni], acc[mi][ni], 0, 0, 0);
  }
  for (int ni = 0; ni < 4; ++ni) {
    int coll = wn + ni * 16 + l15;
    int col = bn0 + coll;
    float bv = bias[col];
    float s = 0.f, q = 0.f;
    for (int mi = 0; mi < 4; ++mi) {
      for (int r = 0; r < 4; ++r) {
        int row = bm0 + wm + mi * 16 + quad * 4 + r;
        float v = acc[mi][ni][r] + bv;
        if (RELU) v = fmaxf(v, 0.f);
        if (RSCALE) v *= rowscale[row];
        C[(size_t)row * Ntot + col] = f2bf(v);
        if (STATS) { s += v; q += v * v; }
      }
    }
    if (STATS) { atomicAdd(&ssum[coll], s); atomicAdd(&ssq[coll], q); }
  }
  if (STATS) {
    __syncthreads();
    int sp = blockIdx.x & 7;
    if (tid < BN) {
      atomicAdd(&stat[(bn0 + tid) * 8 + sp], ssum[tid]);
      atomicAdd(&stat[(DFEAT + bn0 + tid) * 8 + sp], ssq[tid]);
    }
  }
}

// ---------------- chunked, XCD-affine GCN aggregation, 8-deep batched -------
// XWs rows prescaled by disq: RC[n] = relu(disq[n] * (XWs[n] + sum_s XWs[s]) + b)
__global__ __launch_bounds__(256) void aggregate_kernel(
    const uint32* __restrict__ XWs, const int* __restrict__ csr,
    const int* __restrict__ row_start, const float* __restrict__ disq,
    const float* __restrict__ bconv, uint32* __restrict__ RC2,
    float* __restrict__ stat) {
  int bx = blockIdx.x;
  int slot = bx & 7, g = bx >> 3;
  int chunk = slot < 6 ? slot : (slot == 6 ? 0 : 3);
  int noff = slot < 6 ? 0 : 16384;
  int ngrp = (slot == 0 || slot == 3 || slot >= 6) ? 512 : 1024;
  if (g >= ngrp) return;
  __shared__ float ssum[64], ssq[64];
  int tid = threadIdx.x;
  if (tid < 64) { ssum[tid] = 0.f; ssq[tid] = 0.f; }
  __syncthreads();
  int lane = tid & 63, wave = tid >> 6;
  int half = lane >> 5, cl = lane & 31;
  int hb = half << 5;
  int cbase = chunk * 32;
  float b0 = bconv[chunk * 64 + 2 * cl], b1 = bconv[chunk * 64 + 2 * cl + 1];
  float ls0 = 0.f, ls1 = 0.f, lq0 = 0.f, lq1 = 0.f;
  int nodebase = noff + (g * 4 + wave) * 8;
  for (int ni = 0; ni < 8; ++ni) {
    int n = nodebase + ni;
    int beg = row_start[n], end = row_start[n + 1];
    int deg = end - beg;
    int len0 = (deg + 1) >> 1;  // half 0 gets the longer part
    int myBeg = beg + (half ? len0 : 0);
    int myLen = half ? (deg - len0) : len0;
    float a0, a1;
    if (half == 0) {
      uint32 v = XWs[(size_t)n * 192 + cbase + cl];
      a0 = bflo(v); a1 = bfhi(v);
    } else { a0 = 0.f; a1 = 0.f; }
    for (int bb0 = 0; bb0 < len0; bb0 += 32) {
      int rem = myLen - bb0;
      int idx = (cl < rem) ? csr[myBeg + bb0 + cl] : -1;
      int jmax = min(32, len0 - bb0);  // uniform over wave
      int j = 0;
      for (; j + 8 <= jmax; j += 8) {
        uint32 v[8];
#pragma unroll
        for (int jj = 0; jj < 8; ++jj) {
          int s = __shfl(idx, hb + j + jj, 64);
          int sa = (s < 0) ? 0 : s;                 // safe address
          uint32 m = (s < 0) ? 0u : 0xffffffffu;    // zero-mask invalid
          v[jj] = XWs[(size_t)sa * 192 + cbase + cl] & m;
        }
#pragma unroll
        for (int jj = 0; jj < 8; ++jj) { a0 += bflo(v[jj]); a1 += bfhi(v[jj]); }
      }
      for (; j < jmax; ++j) {
        int s = __shfl(idx, hb + j, 64);
        int sa = (s < 0) ? 0 : s;
        uint32 m = (s < 0) ? 0u : 0xffffffffu;
        uint32 v = XWs[(size_t)sa * 192 + cbase + cl] & m;
        a0 += bflo(v); a1 += bfhi(v);
      }
    }
    a0 += __shfl_xor(a0, 32, 64);
    a1 += __shfl_xor(a1, 32, 64);
    if (half == 0) {
      float din = disq[n];
      a0 = fmaxf(din * a0 + b0, 0.f);
      a1 = fmaxf(din * a1 + b1, 0.f);
      RC2[(size_t)n * 192 + cbase + cl] = (uint32)f2bf(a0) | ((uint32)f2bf(a1) << 16);
      ls0 += a0; lq0 += a0 * a0; ls1 += a1; lq1 += a1 * a1;
    }
  }
  if (half == 0) {
    atomicAdd(&ssum[2 * cl], ls0); atomicAdd(&ssum[2 * cl + 1], ls1);
    atomicAdd(&ssq[2 * cl], lq0);  atomicAdd(&ssq[2 * cl + 1], lq1);
  }
  __syncthreads();
  if (tid < 64) {
    int col = chunk * 64 + tid;
    int sp = g & 7;
    atomicAdd(&stat[col * 8 + sp], ssum[tid]);
    atomicAdd(&stat[(DFEAT + col) * 8 + sp], ssq[tid]);
  }
}

// ---------------- gather 2 masked nodes/sample + inline BN6 -> flat f32 -----
__global__ void gather_kernel(const int* __restrict__ mask, const ushort16* __restrict__ R5,
                              const float* __restrict__ stat, const float* __restrict__ g,
                              const float* __restrict__ bb, float invN,
                              float* __restrict__ flat) {
  __shared__ int smin, smax;
  int b = blockIdx.x, t = threadIdx.x;  // 384
  if (t == 0) { smin = 1 << 30; smax = -1; }
  __syncthreads();
  for (int p = t; p < 512; p += 384)
    if (mask[b * 512 + p]) { atomicMin(&smin, p); atomicMax(&smax, p); }
  __syncthreads();
  float s = 0.f, q = 0.f;
  for (int i = 0; i < 8; ++i) { s += stat[t * 8 + i]; q += stat[(DFEAT + t) * 8 + i]; }
  float mean = s * invN, var = q * invN - mean * mean;
  float a = g[t] * rsqrtf(var + 1e-5f), sh = bb[t] - a * mean;
  int sel[2] = {smin, smax};
  for (int j = 0; j < 2; ++j) {
    float v = bf2f(R5[(size_t)(b * 512 + sel[j]) * DFEAT + t]);
    flat[(size_t)b * 768 + j * DFEAT + t] = a * v + sh;
  }
}

// ---------------- tail ------------------------------------------------------
// catrelu[b][j] = relu(flat[b]·Wc[:,j] + bc[j]); grid (12,4) x 1024
__global__ void cat_gemm_kernel(const float* __restrict__ flat, const float* __restrict__ Wc,
                                const float* __restrict__ bc, float* __restrict__ out) {
  int t = threadIdx.x;
  int j = blockIdx.x * 64 + (t & 63);
  int b = blockIdx.y * 16 + (t >> 6);
  const float* fr = flat + (size_t)b * 768;
  float acc = bc[j];
#pragma unroll 4
  for (int k = 0; k < 768; ++k) acc += fr[k] * Wc[(size_t)k * 768 + j];
  out[(size_t)b * 768 + j] = fmaxf(acc, 0.f);
}
// batch-BN affines for cat & H branches; grid 12 x 64
__global__ void bnstats_kernel(const float* __restrict__ catrelu, const float* __restrict__ Hsent,
                               const float* __restrict__ g, const float* __restrict__ bb,
                               float* __restrict__ aff) {
  int c = blockIdx.x * 64 + threadIdx.x;
  float s1 = 0, q1 = 0, s2 = 0, q2 = 0;
  for (int b = 0; b < 64; ++b) {
    float v = catrelu[b * 768 + c]; s1 += v; q1 += v * v;
    float h = Hsent[b * 768 + c];   s2 += h; q2 += h * h;
  }
  const float inv = 1.0f / 64.0f;
  float m1 = s1 * inv, var1 = q1 * inv - m1 * m1;
  float a1 = g[c] * rsqrtf(var1 + 1e-5f);
  aff[c] = a1; aff[768 + c] = bb[c] - a1 * m1;
  float m2 = s2 * inv, var2 = q2 * inv - m2 * m2;
  float a2 = g[768 + c] * rsqrtf(var2 + 1e-5f);
  aff[1536 + c] = a2; aff[2304 + c] = bb[768 + c] - a2 * m2;
}
__global__ void final_kernel(const float* __restrict__ Hs, const float* __restrict__ catrelu,
                             const float* __restrict__ aff, const float* __restrict__ w_out,
                             const float* __restrict__ b_out, float* __restrict__ out) {
  __shared__ float red[12];
  int b = blockIdx.x, t = threadIdx.x;  // 256
  float p0 = 0, p1 = 0, p2 = 0;
  for (int k = t; k < 768; k += 256) {
    float att = (aff[1536 + k] * Hs[b * 768 + k] + aff[2304 + k]) +
                (aff[k] * catrelu[b * 768 + k] + aff[768 + k]);
    p0 += att * w_out[k * 3 + 0];
    p1 += att * w_out[k * 3 + 1];
    p2 += att * w_out[k * 3 + 2];
  }
  for (int off = 32; off > 0; off >>= 1) {
    p0 += __shfl_down(p0, off, 64);
    p1 += __shfl_down(p1, off, 64);
    p2 += __shfl_down(p2, off, 64);
  }
  int wv = t >> 6;
  if ((t & 63) == 0) { red[wv * 3 + 0] = p0; red[wv * 3 + 1] = p1; red[wv * 3 + 2] = p2; }
  __syncthreads();
  if (t == 0) {
    out[b * 3 + 0] = b_out[0] + red[0] + red[3] + red[6] + red[9];
    out[b * 3 + 1] = b_out[1] + red[1] + red[4] + red[7] + red[10];
    out[b * 3 + 2] = b_out[2] + red[2] + red[5] + red[8] + red[11];
  }
}

// ============================================================================
extern "C" void kernel_launch(void* const* d_in, const int* in_sizes, int n_in,
                              void* d_out, int out_size, void* d_ws, size_t ws_size,
                              hipStream_t stream) {
  const float* last_h  = (const float*)d_in[0];
  const float* first_h = (const float*)d_in[1];
  const float* x_nodes = (const float*)d_in[2];
  const int*   edges   = (const int*)d_in[3];
  const int*   mask    = (const int*)d_in[4];
  const float* w_pre1  = (const float*)d_in[5];
  const float* b_pre1  = (const float*)d_in[6];
  const float* w_pre2  = (const float*)d_in[7];
  const float* b_pre2  = (const float*)d_in[8];
  const float* w_conv  = (const float*)d_in[9];
  const float* b_conv  = (const float*)d_in[10];
  const float* bng_g   = (const float*)d_in[11];
  const float* bng_b   = (const float*)d_in[12];
  const float* w_post1 = (const float*)d_in[13];
  const float* b_post1 = (const float*)d_in[14];
  const float* w_post2 = (const float*)d_in[15];
  const float* b_post2 = (const float*)d_in[16];
  const float* w_cat   = (const float*)d_in[17];
  const float* b_cat   = (const float*)d_in[18];
  const float* bn_g    = (const float*)d_in[19];
  const float* bn_b    = (const float*)d_in[20];
  const float* w_out   = (const float*)d_in[21];
  const float* b_out   = (const float*)d_in[22];
  float* out = (float*)d_out;

  const int E = in_sizes[3] / 2;  // 1048576
  const int* e_src = edges;
  const int* e_dst = edges + E;

  char* w = (char*)d_ws;
  size_t off = 0;
  auto alloc = [&](size_t bytes) { size_t p = off; off = (off + bytes + 255) & ~(size_t)255; return p; };
  ushort16* buf0   = (ushort16*)(w + alloc((size_t)NNODES * DFEAT * 2));  // A0, R2, RC, R5
  ushort16* buf1   = (ushort16*)(w + alloc((size_t)NNODES * DFEAT * 2));  // R1, XW', R4
  int*    csr      = (int*)(w + alloc((size_t)E * 4));
  int*    rowstart = (int*)(w + alloc((size_t)(NNODES + 1) * 4));
  int*    cursor   = (int*)(w + alloc((size_t)NNODES * 4));
  float*  disq     = (float*)(w + alloc((size_t)NNODES * 4));
  ushort16* BT     = (ushort16*)(w + alloc((size_t)DFEAT * DFEAT * 2));
  float*  biasx    = (float*)(w + alloc(DFEAT * 4));
  float*  flat     = (float*)(w + alloc(64 * 768 * 4));
  float*  catrelu  = (float*)(w + alloc(64 * 768 * 4));
  float*  aff64    = (float*)(w + alloc(4 * 768 * 4));
  float*  Hpart    = (float*)(w + alloc((size_t)16 * 64 * 768 * 4));
  float*  Hsent    = (float*)(w + alloc(64 * 768 * 4));
  size_t zoff = off;
  int*   degcnt = (int*)(w + alloc((size_t)NNODES * 4));
  float* stats  = (float*)(w + alloc((size_t)5 * 768 * 8 * 4));
  size_t zbytes = off - zoff;

  hipMemsetAsync(w + zoff, 0, zbytes, stream);

  const float invN = 1.0f / (float)NNODES;
  float* st0 = stats + 0 * 768 * 8;
  float* st1 = stats + 1 * 768 * 8;
  float* st2 = stats + 2 * 768 * 8;
  float* st3 = stats + 3 * 768 * 8;
  float* st4 = stats + 4 * 768 * 8;

  // ---- phase A: independent prep ----
  convert_x_kernel<<<NNODES / 4, 256, 0, stream>>>(x_nodes, buf0);
  xform_w_kernel<<<DFEAT, 128, 0, stream>>>(w_pre1, b_pre1, nullptr, nullptr, nullptr, invN, BT, biasx, 300, KPAD1, DFEAT);
  sent_mean_kernel<<<dim3(64, 16), 768, 0, stream>>>(last_h, first_h, Hpart);
  hsent_kernel<<<64, 768, 0, stream>>>(Hpart, Hsent);
  deg_count_kernel<<<(E + 255) / 256, 256, 0, stream>>>(e_dst, degcnt, E);
  disq_kernel<<<NNODES / 256, 256, 0, stream>>>(degcnt, disq);
  scan_kernel<<<1, 1024, 0, stream>>>(degcnt, rowstart, cursor);
  scatter_kernel<<<(E + 255) / 256, 256, 0, stream>>>(e_src, e_dst, cursor, csr, E);

  dim3 ggrid(NNODES / BM, DFEAT / BN);

  // ---- GEMM1: R1 = relu(x @ W1 + b1), stats->BN0 ----
  gemm_bf16<true, true, false><<<ggrid, 256, 0, stream>>>(buf0, KPAD1, BT, KPAD1, biasx, nullptr, buf1, DFEAT, KPAD1, st0);
  xform_w_kernel<<<DFEAT, 128, 0, stream>>>(w_pre2, b_pre2, st0, bng_g + 0 * DFEAT, bng_b + 0 * DFEAT, invN, BT, biasx, DFEAT, DFEAT, DFEAT);

  // ---- GEMM2: R2 = relu(BN0(R1) @ W2 + b2), stats->BN1 ----
  gemm_bf16<true, true, false><<<ggrid, 256, 0, stream>>>(buf1, DFEAT, BT, DFEAT, biasx, nullptr, buf0, DFEAT, DFEAT, st1);
  xform_w_kernel<<<DFEAT, 128, 0, stream>>>(w_conv + 2 * DFEAT * DFEAT, nullptr, st1, bng_g + 1 * DFEAT, bng_b + 1 * DFEAT, invN, BT, biasx, DFEAT, DFEAT, DFEAT);

  // ---- GEMM3: XW' = disq[row] * (BN1(R2) @ Wc)  (conv i=2 only survives) ----
  gemm_bf16<false, false, true><<<ggrid, 256, 0, stream>>>(buf0, DFEAT, BT, DFEAT, biasx, disq, buf1, DFEAT, DFEAT, nullptr);

  // ---- aggregation (chunked, XCD-affine, 8-deep batched), stats->BN4 ----
  aggregate_kernel<<<8192, 256, 0, stream>>>((const uint32*)buf1, csr, rowstart, disq, b_conv + 2 * DFEAT, (uint32*)buf0, st2);
  xform_w_kernel<<<DFEAT, 128, 0, stream>>>(w_post1, b_post1, st2, bng_g + 4 * DFEAT, bng_b + 4 * DFEAT, invN, BT, biasx, DFEAT, DFEAT, DFEAT);

  // ---- GEMM4: R4 = relu(BN4(RC) @ Wp1 + bp1), stats->BN5 ----
  gemm_bf16<true, true, false><<<ggrid, 256, 0, stream>>>(buf0, DFEAT, BT, DFEAT, biasx, nullptr, buf1, DFEAT, DFEAT, st3);
  xform_w_kernel<<<DFEAT, 128, 0, stream>>>(w_post2, b_post2, st3, bng_g + 5 * DFEAT, bng_b + 5 * DFEAT, invN, BT, biasx, DFEAT, DFEAT, DFEAT);

  // ---- GEMM5: R5 = relu(BN5(R4) @ Wp2 + bp2), stats->BN6 ----
  gemm_bf16<true, true, false><<<ggrid, 256, 0, stream>>>(buf1, DFEAT, BT, DFEAT, biasx, nullptr, buf0, DFEAT, DFEAT, st4);

  // ---- gather (BN6 inline) + tail ----
  gather_kernel<<<64, DFEAT, 0, stream>>>(mask, buf0, st4, bng_g + 6 * DFEAT, bng_b + 6 * DFEAT, invN, flat);
  cat_gemm_kernel<<<dim3(12, 4), 1024, 0, stream>>>(flat, w_cat, b_cat, catrelu);
  bnstats_kernel<<<12, 64, 0, stream>>>(catrelu, Hsent, bn_g, bn_b, aff64);
  final_kernel<<<64, 256, 0, stream>>>(Hsent, catrelu, aff64, w_out, b_out, out);
}